// Round 20
// baseline (34.270 us; speedup 1.0000x reference)
//
#include <hip/hip_runtime.h>

#define TWO_N 8192
#define HALF_N 4096
#define DIM 256
#define PANEL8 4096                          // 16 rows x 256 el x 1B (fp8)

#define NBLK 64                              // 8192 / 128 row-blocks
#define ROWS_PER_BLOCK 128
#define CH_COLS 128
#define CHUNK8 (CH_COLS * DIM)               // 32 KB (8 panels = 1 tile)

#define KAPPA 14.426950408889634f            // 10*log2(e)
#define SQRT_KAPPA 3.7982825697f
#define LN2 0.6931471805599453f

typedef __attribute__((ext_vector_type(4))) float f32x4;
typedef __attribute__((ext_vector_type(8))) int i32x8;

__device__ __forceinline__ void async_copy16(void* lds_dst, const void* g_src) {
  __builtin_amdgcn_global_load_lds(
      (const __attribute__((address_space(1))) unsigned int*)g_src,
      (__attribute__((address_space(3))) unsigned int*)lds_dst, 16, 0, 0);
}

// rn8 layout (fragment-major fp8 e4m3 for 16x16x128 MFMA): panel p (16 rows,
// 4096 B). Byte address within panel: kh*2048 + piece*1024 + (g*16+r)*16 + j
// holds row r, k = kh*128 + g*32 + piece*16 + j. Lane l = g*16+r reads its
// 32-byte K-half fragment as two 16-B pieces at l*16 / l*16+1024 -> each
// ds_read_b128 covers a contiguous 1 KB (conflict-free). A and B share this
// scheme, so any within-fragment k permutation cancels in A.B^T.
// Values are scaled by SQRT_KAPPA, so MFMA dot = KAPPA * cos-sim; the
// exp(-KAPPA) normalizer is folded into K3's lse.

__device__ __forceinline__ i32x8 ld_frag(const char* p) {
  int4 lo = *reinterpret_cast<const int4*>(p);
  int4 hi = *reinterpret_cast<const int4*>(p + 1024);
  i32x8 r;
  r[0] = lo.x; r[1] = lo.y; r[2] = lo.z; r[3] = lo.w;
  r[4] = hi.x; r[5] = hi.y; r[6] = hi.z; r[7] = hi.w;
  return r;
}

// K1: normalize 16 rows (one panel) per block; write fragment-major fp8
// scaled by SQRT_KAPPA. Also zero rowsum and out.
__global__ __launch_bounds__(256) void k_norm(const float* __restrict__ zi,
                                              const float* __restrict__ zj,
                                              unsigned char* __restrict__ rn8,
                                              float* __restrict__ rowsum,
                                              float* __restrict__ out) {
  int p = blockIdx.x;
  int wave = threadIdx.x >> 6, lane = threadIdx.x & 63;
  int rp = wave * 4 + (lane >> 4);           // row within panel
  int row = p * 16 + rp;
  int kslot = lane & 15;                     // 16 elems per thread
  int k0 = kslot * 16;
  if (threadIdx.x < 16) rowsum[p * 16 + threadIdx.x] = 0.0f;
  if (p == 0 && threadIdx.x == 0) out[0] = 0.0f;

  const float* src = (row < HALF_N) ? (zi + (size_t)row * DIM)
                                    : (zj + (size_t)(row - HALF_N) * DIM);
  float4 v0 = *reinterpret_cast<const float4*>(src + k0);
  float4 v1 = *reinterpret_cast<const float4*>(src + k0 + 4);
  float4 v2 = *reinterpret_cast<const float4*>(src + k0 + 8);
  float4 v3 = *reinterpret_cast<const float4*>(src + k0 + 12);
  float ss = v0.x*v0.x + v0.y*v0.y + v0.z*v0.z + v0.w*v0.w
           + v1.x*v1.x + v1.y*v1.y + v1.z*v1.z + v1.w*v1.w
           + v2.x*v2.x + v2.y*v2.y + v2.z*v2.z + v2.w*v2.w
           + v3.x*v3.x + v3.y*v3.y + v3.z*v3.z + v3.w*v3.w;
  #pragma unroll
  for (int m = 1; m <= 8; m <<= 1) ss += __shfl_xor(ss, m, 64);
  float r = rsqrtf(ss) * SQRT_KAPPA;

  int wA = __builtin_amdgcn_cvt_pk_fp8_f32(v0.x * r, v0.y * r, 0, 0);
  wA     = __builtin_amdgcn_cvt_pk_fp8_f32(v0.z * r, v0.w * r, wA, 1);
  int wB = __builtin_amdgcn_cvt_pk_fp8_f32(v1.x * r, v1.y * r, 0, 0);
  wB     = __builtin_amdgcn_cvt_pk_fp8_f32(v1.z * r, v1.w * r, wB, 1);
  int wC = __builtin_amdgcn_cvt_pk_fp8_f32(v2.x * r, v2.y * r, 0, 0);
  wC     = __builtin_amdgcn_cvt_pk_fp8_f32(v2.z * r, v2.w * r, wC, 1);
  int wD = __builtin_amdgcn_cvt_pk_fp8_f32(v3.x * r, v3.y * r, 0, 0);
  wD     = __builtin_amdgcn_cvt_pk_fp8_f32(v3.z * r, v3.w * r, wD, 1);

  int kh = kslot >> 3, g = (kslot >> 1) & 3, piece = kslot & 1;
  char* pb = (char*)rn8 + (size_t)p * PANEL8 + kh * 2048 + piece * 1024 +
             (g * 16 + rp) * 16;
  *reinterpret_cast<int4*>(pb) = make_int4(wA, wB, wC, wD);
}

// K2: symmetric Gram rowsums, MX-scaled fp8 K=128 MFMA (scale = 1.0).
// 128-col chunks = ONE FULL TILE per chunk (32 KB): only 3 mid-loop barriers
// per 512-col span (s=8 spans: zero). Double-buffered LDS (64 KB, 2 blk/CU),
// counted vmcnt (exact under in-order retirement). Diagonal masked here.
// Pairs {bi, bj=bi+dd mod 64}: span s covers dd=4s..4s+3 (s=0 includes the
// diagonal tile), s=8 is dd=32 deduped by bi<32. 576-block grid.
__global__ __launch_bounds__(256, 4) void k_sim(const unsigned char* __restrict__ rn8,
                                                float* __restrict__ rowsum) {
  __shared__ alignas(16) char lds[2][CHUNK8];
  int bi = blockIdx.x;
  int s = blockIdx.y;
  if (s == 8 && bi >= 32) return;            // dedupe dd=32 involution
  const int NT = (s == 8) ? 1 : 4;           // chunks of 128 cols (= tiles)
  int dd0 = s * 4;
  bool sdiag = (s == 0);

  int wave = threadIdx.x >> 6, lane = threadIdx.x & 63;
  int lrow = lane & 15, kgrp = lane >> 4;
  int r0 = bi * ROWS_PER_BLOCK + wave * 32;
  const char* base = (const char*)rn8;

  // A: 2 strips (32 rows) per wave, 2 K-half fragments each (8 VGPR apiece).
  i32x8 a[2][2];
  #pragma unroll
  for (int st = 0; st < 2; ++st) {
    const char* pa = base + (size_t)(bi * 8 + wave * 2 + st) * PANEL8 + lane * 16;
    #pragma unroll
    for (int kh = 0; kh < 2; ++kh)
      a[st][kh] = ld_frag(pa + kh * 2048);
  }

  float se[2][4];
  #pragma unroll
  for (int st = 0; st < 2; ++st)
    #pragma unroll
    for (int g = 0; g < 4; ++g) se[st][g] = 0.0f;

  // stage chunk ch (one 128-col tile, 8 panels) into lds[buf]; 8 KB/wave.
  auto stage = [&](int buf, int ch) {
    int bj = (bi + dd0 + ch) & (NBLK - 1);
    const char* gp = base + (size_t)bj * 8 * PANEL8 + wave * 8192 + lane * 16;
    char* dst = &lds[buf][wave * 8192];
    #pragma unroll
    for (int q = 0; q < 8; ++q)
      async_copy16(dst + q * 1024, gp + q * 1024);
  };

  stage(0, 0);
  asm volatile("s_waitcnt vmcnt(0)" ::: "memory");   // chunk 0 landed
  __builtin_amdgcn_s_barrier();

  for (int ch = 0; ch < NT; ++ch) {
    if (ch + 1 < NT) stage((ch + 1) & 1, ch + 1);
    const char* lb = lds[ch & 1] + lane * 16;
    int bjc = (bi + dd0 + ch) & (NBLK - 1);
    bool dtile = sdiag && (ch == 0);                 // diagonal tile bi==bj
    #pragma unroll
    for (int h = 0; h < 8; ++h) {
      int colb = h * 16;                             // tile-local col base
      bool d0 = dtile && (colb == wave * 32);        // diag hits strip 0
      bool d1 = dtile && (colb == wave * 32 + 16);   // diag hits strip 1
      i32x8 b0 = ld_frag(lb + h * 4096);             // K-half 0
      i32x8 b1 = ld_frag(lb + h * 4096 + 2048);      // K-half 1
      f32x4 acc0 = {0.f, 0.f, 0.f, 0.f};
      f32x4 acc1 = {0.f, 0.f, 0.f, 0.f};
      __builtin_amdgcn_s_setprio(1);
      acc0 = __builtin_amdgcn_mfma_scale_f32_16x16x128_f8f6f4(
                 a[0][0], b0, acc0, 0, 0, 0, 127, 0, 127);
      acc0 = __builtin_amdgcn_mfma_scale_f32_16x16x128_f8f6f4(
                 a[0][1], b1, acc0, 0, 0, 0, 127, 0, 127);
      acc1 = __builtin_amdgcn_mfma_scale_f32_16x16x128_f8f6f4(
                 a[1][0], b0, acc1, 0, 0, 0, 127, 0, 127);
      acc1 = __builtin_amdgcn_mfma_scale_f32_16x16x128_f8f6f4(
                 a[1][1], b1, acc1, 0, 0, 0, 127, 0, 127);
      __builtin_amdgcn_s_setprio(0);
      float scc = 0.0f;
      #pragma unroll
      for (int g = 0; g < 4; ++g) {
        float e0 = __builtin_amdgcn_exp2f(acc0[g]);   // = 2^(kappa*d)
        float e1 = __builtin_amdgcn_exp2f(acc1[g]);
        if (d0 && lrow == kgrp * 4 + g) e0 = 0.0f;    // diag (strip 0)
        if (d1 && lrow == kgrp * 4 + g) e1 = 0.0f;    // diag (strip 1)
        se[0][g] += e0;
        se[1][g] += e1;
        scc += e0 + e1;
      }
      if (!dtile) {
        // column sums of this 16-col panel -> rows of bjc (transposed tile)
        scc += __shfl_xor(scc, 16, 64);
        scc += __shfl_xor(scc, 32, 64);
        if (lane < 16)
          atomicAdd(&rowsum[bjc * ROWS_PER_BLOCK + colb + lane], scc);
      }
    }
    if (ch + 1 < NT) {
      // counted drain (in-order retirement): stage(ch+1)'s 8 loads retired;
      // this chunk's 8 col atomics (younger) stay in flight. Diag chunk
      // issued no atomics -> full drain is free.
      if (dtile)
        asm volatile("s_waitcnt vmcnt(0)" ::: "memory");
      else
        asm volatile("s_waitcnt vmcnt(8)" ::: "memory");
      __builtin_amdgcn_s_barrier();
    }
  }

  // row sums: reduce over 16 column-lanes, one atomic per row
  #pragma unroll
  for (int st = 0; st < 2; ++st) {
    #pragma unroll
    for (int g = 0; g < 4; ++g) {
      float v = se[st][g];
      #pragma unroll
      for (int m = 1; m <= 8; m <<= 1) v += __shfl_xor(v, m, 64);
      if (lrow == 0) atomicAdd(&rowsum[r0 + 16 * st + kgrp * 4 + g], v);
    }
  }
}

// K3: per pair (i, j=i+N): lse - pos for both rows (diag already masked).
// rowsum is 2^KAPPA-scaled: lse = 10 + LN2*(log2(rowsum) - KAPPA).
// Stored data is sqrt(kappa)-scaled: dp = KAPPA*d -> pos = LN2*dp.
__global__ __launch_bounds__(256) void k_rowred(const unsigned char* __restrict__ rn8,
                                               const float* __restrict__ rowsum,
                                               float* __restrict__ out) {
  __shared__ float ls[4];
  int wave = threadIdx.x >> 6, lane = threadIdx.x & 63;
  int q = lane & 31;
  const char* base = (const char*)rn8;
  float local = 0.0f;
  #pragma unroll
  for (int t = 0; t < 8; ++t) {
    int i = blockIdx.x * 32 + wave * 8 + t;              // pair 0..4095
    int row = (lane >> 5) ? i + HALF_N : i;
    int sl = q >> 1, jo = (q & 1) * 8;
    const char* addr = base + (size_t)(row >> 4) * PANEL8 + (sl >> 3) * 2048 +
                       ((sl >> 2) & 1) * 1024 + ((sl & 3) * 16 + (row & 15)) * 16 + jo;
    int2 own = *reinterpret_cast<const int2*>(addr);
    int px = __shfl_xor(own.x, 32, 64);
    int py = __shfl_xor(own.y, 32, 64);
    float dp =
        __builtin_amdgcn_cvt_f32_fp8(own.x, 0) * __builtin_amdgcn_cvt_f32_fp8(px, 0) +
        __builtin_amdgcn_cvt_f32_fp8(own.x, 1) * __builtin_amdgcn_cvt_f32_fp8(px, 1) +
        __builtin_amdgcn_cvt_f32_fp8(own.x, 2) * __builtin_amdgcn_cvt_f32_fp8(px, 2) +
        __builtin_amdgcn_cvt_f32_fp8(own.x, 3) * __builtin_amdgcn_cvt_f32_fp8(px, 3) +
        __builtin_amdgcn_cvt_f32_fp8(own.y, 0) * __builtin_amdgcn_cvt_f32_fp8(py, 0) +
        __builtin_amdgcn_cvt_f32_fp8(own.y, 1) * __builtin_amdgcn_cvt_f32_fp8(py, 1) +
        __builtin_amdgcn_cvt_f32_fp8(own.y, 2) * __builtin_amdgcn_cvt_f32_fp8(py, 2) +
        __builtin_amdgcn_cvt_f32_fp8(own.y, 3) * __builtin_amdgcn_cvt_f32_fp8(py, 3);
    #pragma unroll
    for (int m = 1; m <= 16; m <<= 1) dp += __shfl_xor(dp, m, 64);
    if (q == 0) {                     // lanes 0 (row i) and 32 (row j)
      float lse = 10.0f + LN2 * (__builtin_amdgcn_logf(rowsum[row]) - KAPPA);
      local += lse - LN2 * dp;
    }
  }
  local += __shfl_xor(local, 32, 64);
  if (lane == 0) ls[wave] = local;
  __syncthreads();
  if (threadIdx.x == 0)
    atomicAdd(out, (ls[0] + ls[1] + ls[2] + ls[3]) * (1.0f / TWO_N));
}

extern "C" void kernel_launch(void* const* d_in, const int* in_sizes, int n_in,
                              void* d_out, int out_size, void* d_ws, size_t ws_size,
                              hipStream_t stream) {
  const float* zi = (const float*)d_in[0];
  const float* zj = (const float*)d_in[1];
  unsigned char* rn8 = (unsigned char*)d_ws;                        // 2 MB
  float* rowsum = (float*)((char*)d_ws + (size_t)TWO_N * DIM);      // 32 KB
  float* out = (float*)d_out;

  hipLaunchKernelGGL(k_norm, dim3(TWO_N / 16), dim3(256), 0, stream,
                     zi, zj, rn8, rowsum, out);
  hipLaunchKernelGGL(k_sim, dim3(NBLK, 9), dim3(256), 0, stream, rn8, rowsum);
  hipLaunchKernelGGL(k_rowred, dim3(HALF_N / 32), dim3(256), 0, stream,
                     rn8, rowsum, out);
}

// Round 21
// 32.577 us; speedup vs baseline: 1.0520x; 1.0520x over previous
//
#include <hip/hip_runtime.h>

#define TWO_N 8192
#define HALF_N 4096
#define DIM 256
#define PANEL8 4096                          // 16 rows x 256 el x 1B (fp8)

#define NBLK 64                              // 8192 / 128 row-blocks
#define ROWS_PER_BLOCK 128
#define CH_COLS 64
#define CHUNK8 (CH_COLS * DIM)               // 16 KB (4 panels)

#define KAPPA 14.426950408889634f            // 10*log2(e)
#define SQRT_KAPPA 3.7982825697f
#define LN2 0.6931471805599453f

typedef __attribute__((ext_vector_type(4))) float f32x4;
typedef __attribute__((ext_vector_type(8))) int i32x8;

__device__ __forceinline__ void async_copy16(void* lds_dst, const void* g_src) {
  __builtin_amdgcn_global_load_lds(
      (const __attribute__((address_space(1))) unsigned int*)g_src,
      (__attribute__((address_space(3))) unsigned int*)lds_dst, 16, 0, 0);
}

// rn8 layout (fragment-major fp8 e4m3 for 16x16x128 MFMA): panel p (16 rows,
// 4096 B). Byte address within panel: kh*2048 + piece*1024 + (g*16+r)*16 + j
// holds row r, k = kh*128 + g*32 + piece*16 + j. Lane l = g*16+r reads its
// 32-byte K-half fragment as two 16-B pieces at l*16 / l*16+1024 -> each
// ds_read_b128 covers a contiguous 1 KB (conflict-free). A and B share this
// scheme, so any within-fragment k permutation cancels in A.B^T.
// Values are scaled by SQRT_KAPPA, so MFMA dot = KAPPA * cos-sim; the
// exp(-KAPPA) normalizer is folded into K3's lse.

__device__ __forceinline__ i32x8 ld_frag(const char* p) {
  int4 lo = *reinterpret_cast<const int4*>(p);
  int4 hi = *reinterpret_cast<const int4*>(p + 1024);
  i32x8 r;
  r[0] = lo.x; r[1] = lo.y; r[2] = lo.z; r[3] = lo.w;
  r[4] = hi.x; r[5] = hi.y; r[6] = hi.z; r[7] = hi.w;
  return r;
}

// K1: normalize 16 rows (one panel) per block; write fragment-major fp8
// scaled by SQRT_KAPPA. Also zero rowsum and out.
__global__ __launch_bounds__(256) void k_norm(const float* __restrict__ zi,
                                              const float* __restrict__ zj,
                                              unsigned char* __restrict__ rn8,
                                              float* __restrict__ rowsum,
                                              float* __restrict__ out) {
  int p = blockIdx.x;
  int wave = threadIdx.x >> 6, lane = threadIdx.x & 63;
  int rp = wave * 4 + (lane >> 4);           // row within panel
  int row = p * 16 + rp;
  int kslot = lane & 15;                     // 16 elems per thread
  int k0 = kslot * 16;
  if (threadIdx.x < 16) rowsum[p * 16 + threadIdx.x] = 0.0f;
  if (p == 0 && threadIdx.x == 0) out[0] = 0.0f;

  const float* src = (row < HALF_N) ? (zi + (size_t)row * DIM)
                                    : (zj + (size_t)(row - HALF_N) * DIM);
  float4 v0 = *reinterpret_cast<const float4*>(src + k0);
  float4 v1 = *reinterpret_cast<const float4*>(src + k0 + 4);
  float4 v2 = *reinterpret_cast<const float4*>(src + k0 + 8);
  float4 v3 = *reinterpret_cast<const float4*>(src + k0 + 12);
  float ss = v0.x*v0.x + v0.y*v0.y + v0.z*v0.z + v0.w*v0.w
           + v1.x*v1.x + v1.y*v1.y + v1.z*v1.z + v1.w*v1.w
           + v2.x*v2.x + v2.y*v2.y + v2.z*v2.z + v2.w*v2.w
           + v3.x*v3.x + v3.y*v3.y + v3.z*v3.z + v3.w*v3.w;
  #pragma unroll
  for (int m = 1; m <= 8; m <<= 1) ss += __shfl_xor(ss, m, 64);
  float r = rsqrtf(ss) * SQRT_KAPPA;

  int wA = __builtin_amdgcn_cvt_pk_fp8_f32(v0.x * r, v0.y * r, 0, 0);
  wA     = __builtin_amdgcn_cvt_pk_fp8_f32(v0.z * r, v0.w * r, wA, 1);
  int wB = __builtin_amdgcn_cvt_pk_fp8_f32(v1.x * r, v1.y * r, 0, 0);
  wB     = __builtin_amdgcn_cvt_pk_fp8_f32(v1.z * r, v1.w * r, wB, 1);
  int wC = __builtin_amdgcn_cvt_pk_fp8_f32(v2.x * r, v2.y * r, 0, 0);
  wC     = __builtin_amdgcn_cvt_pk_fp8_f32(v2.z * r, v2.w * r, wC, 1);
  int wD = __builtin_amdgcn_cvt_pk_fp8_f32(v3.x * r, v3.y * r, 0, 0);
  wD     = __builtin_amdgcn_cvt_pk_fp8_f32(v3.z * r, v3.w * r, wD, 1);

  int kh = kslot >> 3, g = (kslot >> 1) & 3, piece = kslot & 1;
  char* pb = (char*)rn8 + (size_t)p * PANEL8 + kh * 2048 + piece * 1024 +
             (g * 16 + rp) * 16;
  *reinterpret_cast<int4*>(pb) = make_int4(wA, wB, wC, wD);
}

// K2: symmetric Gram rowsums, MX-scaled fp8 K=128 MFMA (scale = 1.0).
// 64-col chunks (16 KB, 4 half-panels), tri-buffered LDS (48 KB, up to
// 3 blk/CU), counted vmcnt (exact under in-order retirement). Diagonal
// masked here. Pairs {bi, bj=bi+dd mod 64}: span s covers dd=4s..4s+3
// (s=0 includes the diagonal tile), s=8 is dd=32 deduped by bi<32.
// 576-block grid (~2.25/CU): concurrency beats uniformity (R17/R20 lessons).
__global__ __launch_bounds__(256, 4) void k_sim(const unsigned char* __restrict__ rn8,
                                                float* __restrict__ rowsum) {
  __shared__ alignas(16) char lds[3][CHUNK8];
  int bi = blockIdx.x;
  int s = blockIdx.y;
  if (s == 8 && bi >= 32) return;            // dedupe dd=32 involution
  const int NT = (s == 8) ? 2 : 8;           // chunks of 64 cols
  int dd0 = s * 4;
  bool sdiag = (s == 0);

  int wave = threadIdx.x >> 6, lane = threadIdx.x & 63;
  int lrow = lane & 15, kgrp = lane >> 4;
  int r0 = bi * ROWS_PER_BLOCK + wave * 32;
  const char* base = (const char*)rn8;

  // A: 2 strips (32 rows) per wave, 2 K-half fragments each (8 VGPR apiece).
  i32x8 a[2][2];
  #pragma unroll
  for (int st = 0; st < 2; ++st) {
    const char* pa = base + (size_t)(bi * 8 + wave * 2 + st) * PANEL8 + lane * 16;
    #pragma unroll
    for (int kh = 0; kh < 2; ++kh)
      a[st][kh] = ld_frag(pa + kh * 2048);
  }

  float se[2][4];
  #pragma unroll
  for (int st = 0; st < 2; ++st)
    #pragma unroll
    for (int g = 0; g < 4; ++g) se[st][g] = 0.0f;

  // stage chunk ch (64 cols = 4 panels of tile ch>>1) into lds[buf]; linear.
  auto stage = [&](int buf, int ch) {
    int bj = (bi + dd0 + (ch >> 1)) & (NBLK - 1);
    const char* gp = base + ((size_t)bj * 8 + (size_t)(ch & 1) * 4) * PANEL8 +
                     wave * 4096 + lane * 16;
    char* dst = &lds[buf][wave * 4096];
    async_copy16(dst, gp);
    async_copy16(dst + 1024, gp + 1024);
    async_copy16(dst + 2048, gp + 2048);
    async_copy16(dst + 3072, gp + 3072);
  };

  stage(0, 0);
  stage(1, 1);
  asm volatile("s_waitcnt vmcnt(4)" ::: "memory");   // chunk 0 landed
  __builtin_amdgcn_s_barrier();

  for (int ch = 0; ch < NT; ++ch) {
    if (ch + 2 < NT) stage((ch + 2) % 3, ch + 2);
    const char* lb = lds[ch % 3] + lane * 16;
    int bjc = (bi + dd0 + (ch >> 1)) & (NBLK - 1);
    bool dtile = sdiag && ((ch >> 1) == 0);          // diagonal tile bi==bj
    #pragma unroll
    for (int h = 0; h < 4; ++h) {
      int colb = (ch & 1) * 64 + h * 16;             // tile-local col base
      bool d0 = dtile && (colb == wave * 32);        // diag hits strip 0
      bool d1 = dtile && (colb == wave * 32 + 16);   // diag hits strip 1
      i32x8 b0 = ld_frag(lb + h * 4096);             // K-half 0
      i32x8 b1 = ld_frag(lb + h * 4096 + 2048);      // K-half 1
      f32x4 acc0 = {0.f, 0.f, 0.f, 0.f};
      f32x4 acc1 = {0.f, 0.f, 0.f, 0.f};
      __builtin_amdgcn_s_setprio(1);
      acc0 = __builtin_amdgcn_mfma_scale_f32_16x16x128_f8f6f4(
                 a[0][0], b0, acc0, 0, 0, 0, 127, 0, 127);
      acc0 = __builtin_amdgcn_mfma_scale_f32_16x16x128_f8f6f4(
                 a[0][1], b1, acc0, 0, 0, 0, 127, 0, 127);
      acc1 = __builtin_amdgcn_mfma_scale_f32_16x16x128_f8f6f4(
                 a[1][0], b0, acc1, 0, 0, 0, 127, 0, 127);
      acc1 = __builtin_amdgcn_mfma_scale_f32_16x16x128_f8f6f4(
                 a[1][1], b1, acc1, 0, 0, 0, 127, 0, 127);
      __builtin_amdgcn_s_setprio(0);
      float scc = 0.0f;
      #pragma unroll
      for (int g = 0; g < 4; ++g) {
        float e0 = __builtin_amdgcn_exp2f(acc0[g]);   // = 2^(kappa*d)
        float e1 = __builtin_amdgcn_exp2f(acc1[g]);
        if (d0 && lrow == kgrp * 4 + g) e0 = 0.0f;    // diag (strip 0)
        if (d1 && lrow == kgrp * 4 + g) e1 = 0.0f;    // diag (strip 1)
        se[0][g] += e0;
        se[1][g] += e1;
        scc += e0 + e1;
      }
      if (!dtile) {
        // column sums of this 16-col panel -> rows of bjc (transposed tile)
        scc += __shfl_xor(scc, 16, 64);
        scc += __shfl_xor(scc, 32, 64);
        if (lane < 16)
          atomicAdd(&rowsum[bjc * ROWS_PER_BLOCK + colb + lane], scc);
      }
    }
    if (ch + 1 < NT) {
      // counted drain (in-order retirement): ensure chunk ch+1's 4 loads
      // retired; keep chunk ch+2's loads + younger atomics in flight.
      if (ch + 2 < NT) {
        if (sdiag && ch < 2)
          asm volatile("s_waitcnt vmcnt(4)" ::: "memory");   // no atomics yet
        else
          asm volatile("s_waitcnt vmcnt(12)" ::: "memory");  // 4+4+4 younger
      } else {
        if (NT == 2)
          asm volatile("s_waitcnt vmcnt(4)" ::: "memory");
        else
          asm volatile("s_waitcnt vmcnt(8)" ::: "memory");   // 4+4 younger
      }
      __builtin_amdgcn_s_barrier();
    }
  }

  // row sums: reduce over 16 column-lanes, one atomic per row
  #pragma unroll
  for (int st = 0; st < 2; ++st) {
    #pragma unroll
    for (int g = 0; g < 4; ++g) {
      float v = se[st][g];
      #pragma unroll
      for (int m = 1; m <= 8; m <<= 1) v += __shfl_xor(v, m, 64);
      if (lrow == 0) atomicAdd(&rowsum[r0 + 16 * st + kgrp * 4 + g], v);
    }
  }
}

// K3: per pair (i, j=i+N): lse - pos for both rows (diag already masked).
// rowsum is 2^KAPPA-scaled: lse = 10 + LN2*(log2(rowsum) - KAPPA).
// Stored data is sqrt(kappa)-scaled: dp = KAPPA*d -> pos = LN2*dp.
__global__ __launch_bounds__(256) void k_rowred(const unsigned char* __restrict__ rn8,
                                               const float* __restrict__ rowsum,
                                               float* __restrict__ out) {
  __shared__ float ls[4];
  int wave = threadIdx.x >> 6, lane = threadIdx.x & 63;
  int q = lane & 31;
  const char* base = (const char*)rn8;
  float local = 0.0f;
  #pragma unroll
  for (int t = 0; t < 8; ++t) {
    int i = blockIdx.x * 32 + wave * 8 + t;              // pair 0..4095
    int row = (lane >> 5) ? i + HALF_N : i;
    int sl = q >> 1, jo = (q & 1) * 8;
    const char* addr = base + (size_t)(row >> 4) * PANEL8 + (sl >> 3) * 2048 +
                       ((sl >> 2) & 1) * 1024 + ((sl & 3) * 16 + (row & 15)) * 16 + jo;
    int2 own = *reinterpret_cast<const int2*>(addr);
    int px = __shfl_xor(own.x, 32, 64);
    int py = __shfl_xor(own.y, 32, 64);
    float dp =
        __builtin_amdgcn_cvt_f32_fp8(own.x, 0) * __builtin_amdgcn_cvt_f32_fp8(px, 0) +
        __builtin_amdgcn_cvt_f32_fp8(own.x, 1) * __builtin_amdgcn_cvt_f32_fp8(px, 1) +
        __builtin_amdgcn_cvt_f32_fp8(own.x, 2) * __builtin_amdgcn_cvt_f32_fp8(px, 2) +
        __builtin_amdgcn_cvt_f32_fp8(own.x, 3) * __builtin_amdgcn_cvt_f32_fp8(px, 3) +
        __builtin_amdgcn_cvt_f32_fp8(own.y, 0) * __builtin_amdgcn_cvt_f32_fp8(py, 0) +
        __builtin_amdgcn_cvt_f32_fp8(own.y, 1) * __builtin_amdgcn_cvt_f32_fp8(py, 1) +
        __builtin_amdgcn_cvt_f32_fp8(own.y, 2) * __builtin_amdgcn_cvt_f32_fp8(py, 2) +
        __builtin_amdgcn_cvt_f32_fp8(own.y, 3) * __builtin_amdgcn_cvt_f32_fp8(py, 3);
    #pragma unroll
    for (int m = 1; m <= 16; m <<= 1) dp += __shfl_xor(dp, m, 64);
    if (q == 0) {                     // lanes 0 (row i) and 32 (row j)
      float lse = 10.0f + LN2 * (__builtin_amdgcn_logf(rowsum[row]) - KAPPA);
      local += lse - LN2 * dp;
    }
  }
  local += __shfl_xor(local, 32, 64);
  if (lane == 0) ls[wave] = local;
  __syncthreads();
  if (threadIdx.x == 0)
    atomicAdd(out, (ls[0] + ls[1] + ls[2] + ls[3]) * (1.0f / TWO_N));
}

extern "C" void kernel_launch(void* const* d_in, const int* in_sizes, int n_in,
                              void* d_out, int out_size, void* d_ws, size_t ws_size,
                              hipStream_t stream) {
  const float* zi = (const float*)d_in[0];
  const float* zj = (const float*)d_in[1];
  unsigned char* rn8 = (unsigned char*)d_ws;                        // 2 MB
  float* rowsum = (float*)((char*)d_ws + (size_t)TWO_N * DIM);      // 32 KB
  float* out = (float*)d_out;

  hipLaunchKernelGGL(k_norm, dim3(TWO_N / 16), dim3(256), 0, stream,
                     zi, zj, rn8, rowsum, out);
  hipLaunchKernelGGL(k_sim, dim3(NBLK, 9), dim3(256), 0, stream, rn8, rowsum);
  hipLaunchKernelGGL(k_rowred, dim3(HALF_N / 32), dim3(256), 0, stream,
                     rn8, rowsum, out);
}

// Round 22
// 26.964 us; speedup vs baseline: 1.2709x; 1.2081x over previous
//
#include <hip/hip_runtime.h>

#define TWO_N 8192
#define HALF_N 4096
#define DIM 256
#define PANEL4 2048                          // 16 rows x 256 el x 0.5B (fp4)

#define NBLK 64                              // 8192 / 128 row-blocks
#define ROWS_PER_BLOCK 128
#define CH_COLS 64
#define CHUNK4 (CH_COLS * DIM / 2)           // 8 KB (4 panels)

#define KAPPA 14.426950408889634f            // 10*log2(e)
#define KINV  (KAPPA / 256.0f)               // acc = 256*d (store-scale 16)
#define POS_SCALE (10.0f / 256.0f)
#define LN2 0.6931471805599453f

typedef __attribute__((ext_vector_type(4))) float f32x4;
typedef __attribute__((ext_vector_type(8))) int i32x8;

__device__ __forceinline__ void async_copy16(void* lds_dst, const void* g_src) {
  __builtin_amdgcn_global_load_lds(
      (const __attribute__((address_space(1))) unsigned int*)g_src,
      (__attribute__((address_space(3))) unsigned int*)lds_dst, 16, 0, 0);
}

// rn4 layout (fragment-major fp4 e2m1 for 16x16x128 MFMA): panel p (16 rows,
// 2048 B). Byte address within panel: kh*1024 + (g*16+r)*16 + nibble-packed
// 32 k-elements per 16-B lane slot. Lane l = g*16+r reads its 16-B K-half
// fragment with ONE ds_read_b128; a K-half region is a contiguous 1 KB
// (conflict-free). A and B share this scheme, so any within-fragment k
// permutation cancels in A.B^T. Values stored as fp4(16 * x_hat):
// MFMA dot (e8m0 scales = 1.0) = 256 * cos-sim.

// e2m1 round-to-nearest: grid {0,.5,1,1.5,2,3,4,6}, midpoint thresholds.
__device__ __forceinline__ unsigned int fp4e(float x) {
  unsigned int s = (__float_as_uint(x) >> 31) << 3;
  float a = fabsf(x);
  unsigned int c = (a > 0.25f) + (a > 0.75f) + (a > 1.25f) + (a > 1.75f)
                 + (a > 2.5f) + (a > 3.5f) + (a > 5.0f);
  return s | c;
}

__device__ __forceinline__ i32x8 up8(int4 v) {
  i32x8 r;
  r[0] = v.x; r[1] = v.y; r[2] = v.z; r[3] = v.w;
  r[4] = 0; r[5] = 0; r[6] = 0; r[7] = 0;   // fp4 uses regs [0:3] only
  return r;
}

// K1: normalize 16 rows (one panel) per block; write fragment-major fp4
// (values * 16). Also zero rowsum and out.
__global__ __launch_bounds__(256) void k_norm(const float* __restrict__ zi,
                                              const float* __restrict__ zj,
                                              unsigned char* __restrict__ rn4,
                                              float* __restrict__ rowsum,
                                              float* __restrict__ out) {
  int p = blockIdx.x;
  int wave = threadIdx.x >> 6, lane = threadIdx.x & 63;
  int rp = wave * 4 + (lane >> 4);           // row within panel
  int row = p * 16 + rp;
  int kslot = lane & 15;                     // 16 elems per thread
  int k0 = kslot * 16;
  if (threadIdx.x < 16) rowsum[p * 16 + threadIdx.x] = 0.0f;
  if (p == 0 && threadIdx.x == 0) out[0] = 0.0f;

  const float* src = (row < HALF_N) ? (zi + (size_t)row * DIM)
                                    : (zj + (size_t)(row - HALF_N) * DIM);
  float4 v0 = *reinterpret_cast<const float4*>(src + k0);
  float4 v1 = *reinterpret_cast<const float4*>(src + k0 + 4);
  float4 v2 = *reinterpret_cast<const float4*>(src + k0 + 8);
  float4 v3 = *reinterpret_cast<const float4*>(src + k0 + 12);
  float ss = v0.x*v0.x + v0.y*v0.y + v0.z*v0.z + v0.w*v0.w
           + v1.x*v1.x + v1.y*v1.y + v1.z*v1.z + v1.w*v1.w
           + v2.x*v2.x + v2.y*v2.y + v2.z*v2.z + v2.w*v2.w
           + v3.x*v3.x + v3.y*v3.y + v3.z*v3.z + v3.w*v3.w;
  #pragma unroll
  for (int m = 1; m <= 8; m <<= 1) ss += __shfl_xor(ss, m, 64);
  float r = rsqrtf(ss) * 16.0f;              // store-scale 16: sigma = 1

  unsigned int w0 =  fp4e(v0.x * r)        | (fp4e(v0.y * r) << 4)
                  | (fp4e(v0.z * r) << 8)  | (fp4e(v0.w * r) << 12)
                  | (fp4e(v1.x * r) << 16) | (fp4e(v1.y * r) << 20)
                  | (fp4e(v1.z * r) << 24) | (fp4e(v1.w * r) << 28);
  unsigned int w1 =  fp4e(v2.x * r)        | (fp4e(v2.y * r) << 4)
                  | (fp4e(v2.z * r) << 8)  | (fp4e(v2.w * r) << 12)
                  | (fp4e(v3.x * r) << 16) | (fp4e(v3.y * r) << 20)
                  | (fp4e(v3.z * r) << 24) | (fp4e(v3.w * r) << 28);

  int kh = kslot >> 3, g = (kslot >> 1) & 3, piece = kslot & 1;
  char* pb = (char*)rn4 + (size_t)p * PANEL4 + kh * 1024 +
             (g * 16 + rp) * 16 + piece * 8;
  *reinterpret_cast<uint2*>(pb) = make_uint2(w0, w1);
}

// K2: symmetric Gram rowsums, MX fp4 K=128 MFMA (cbsz=blgp=4, scales 1.0).
// 64-col chunks (8 KB), tri-buffered LDS (24 KB), counted vmcnt. Diagonal
// masked here. s=8 (dd=32) tiles harvest the positive-pair dots from their
// tile diagonal into posv (each entry written exactly once). Pairs
// {bi, bj=bi+dd mod 64}: span s covers dd=4s..4s+3 (s=0 includes the diag
// tile), s=8 is dd=32 deduped by bi<32. 576-block grid (~2.25/CU).
__global__ __launch_bounds__(256, 4) void k_sim(const unsigned char* __restrict__ rn4,
                                                float* __restrict__ rowsum,
                                                float* __restrict__ posv) {
  __shared__ alignas(16) char lds[3][CHUNK4];
  int bi = blockIdx.x;
  int s = blockIdx.y;
  if (s == 8 && bi >= 32) return;            // dedupe dd=32 involution
  const int NT = (s == 8) ? 2 : 8;           // chunks of 64 cols
  int dd0 = s * 4;
  bool sdiag = (s == 0);
  bool ptile = (s == 8);                     // positive-pair tile (bi, bi+32)

  int wave = threadIdx.x >> 6, lane = threadIdx.x & 63;
  int lrow = lane & 15, kgrp = lane >> 4;
  int r0 = bi * ROWS_PER_BLOCK + wave * 32;
  const char* base = (const char*)rn4;

  // A: 2 strips (32 rows) per wave, 2 K-half fragments each (4 VGPR apiece).
  int4 a[2][2];
  #pragma unroll
  for (int st = 0; st < 2; ++st) {
    const char* pa = base + (size_t)(bi * 8 + wave * 2 + st) * PANEL4 + lane * 16;
    #pragma unroll
    for (int kh = 0; kh < 2; ++kh)
      a[st][kh] = *reinterpret_cast<const int4*>(pa + kh * 1024);
  }

  float se[2][4];
  #pragma unroll
  for (int st = 0; st < 2; ++st)
    #pragma unroll
    for (int g = 0; g < 4; ++g) se[st][g] = 0.0f;

  // stage chunk ch (64 cols = 4 panels of tile ch>>1); 1 panel per wave.
  auto stage = [&](int buf, int ch) {
    int bj = (bi + dd0 + (ch >> 1)) & (NBLK - 1);
    const char* gp = base + ((size_t)bj * 8 + (size_t)(ch & 1) * 4 + wave) * PANEL4 +
                     lane * 16;
    char* dst = &lds[buf][wave * 2048];
    async_copy16(dst, gp);
    async_copy16(dst + 1024, gp + 1024);
  };

  stage(0, 0);
  stage(1, 1);
  asm volatile("s_waitcnt vmcnt(2)" ::: "memory");   // chunk 0 landed
  __builtin_amdgcn_s_barrier();

  for (int ch = 0; ch < NT; ++ch) {
    if (ch + 2 < NT) stage((ch + 2) % 3, ch + 2);
    const char* lb = lds[ch % 3] + lane * 16;
    int bjc = (bi + dd0 + (ch >> 1)) & (NBLK - 1);
    bool dtile = sdiag && ((ch >> 1) == 0);          // diagonal tile bi==bj
    #pragma unroll
    for (int h = 0; h < 4; ++h) {
      int colb = (ch & 1) * 64 + h * 16;             // tile-local col base
      bool d0 = dtile && (colb == wave * 32);        // diag hits strip 0
      bool d1 = dtile && (colb == wave * 32 + 16);   // diag hits strip 1
      bool p0 = ptile && (colb == wave * 32);        // pos-pair diag, strip 0
      bool p1 = ptile && (colb == wave * 32 + 16);   // pos-pair diag, strip 1
      int4 b0 = *reinterpret_cast<const int4*>(lb + h * 2048);        // kh 0
      int4 b1 = *reinterpret_cast<const int4*>(lb + h * 2048 + 1024); // kh 1
      f32x4 acc0 = {0.f, 0.f, 0.f, 0.f};
      f32x4 acc1 = {0.f, 0.f, 0.f, 0.f};
      __builtin_amdgcn_s_setprio(1);
      acc0 = __builtin_amdgcn_mfma_scale_f32_16x16x128_f8f6f4(
                 up8(a[0][0]), up8(b0), acc0, 4, 4, 0, 127, 0, 127);
      acc0 = __builtin_amdgcn_mfma_scale_f32_16x16x128_f8f6f4(
                 up8(a[0][1]), up8(b1), acc0, 4, 4, 0, 127, 0, 127);
      acc1 = __builtin_amdgcn_mfma_scale_f32_16x16x128_f8f6f4(
                 up8(a[1][0]), up8(b0), acc1, 4, 4, 0, 127, 0, 127);
      acc1 = __builtin_amdgcn_mfma_scale_f32_16x16x128_f8f6f4(
                 up8(a[1][1]), up8(b1), acc1, 4, 4, 0, 127, 0, 127);
      __builtin_amdgcn_s_setprio(0);
      float scc = 0.0f;
      #pragma unroll
      for (int g = 0; g < 4; ++g) {
        float e0 = __builtin_amdgcn_exp2f(acc0[g] * KINV);  // 2^(kappa*d)
        float e1 = __builtin_amdgcn_exp2f(acc1[g] * KINV);
        if (d0 && lrow == kgrp * 4 + g) e0 = 0.0f;    // mask true diagonal
        if (d1 && lrow == kgrp * 4 + g) e1 = 0.0f;
        if (p0 && lrow == kgrp * 4 + g)               // harvest pos dot
          posv[r0 + kgrp * 4 + g] = acc0[g];
        if (p1 && lrow == kgrp * 4 + g)
          posv[r0 + 16 + kgrp * 4 + g] = acc1[g];
        se[0][g] += e0;
        se[1][g] += e1;
        scc += e0 + e1;
      }
      if (!dtile) {
        // column sums of this 16-col panel -> rows of bjc (transposed tile)
        scc += __shfl_xor(scc, 16, 64);
        scc += __shfl_xor(scc, 32, 64);
        if (lane < 16)
          atomicAdd(&rowsum[bjc * ROWS_PER_BLOCK + colb + lane], scc);
      }
    }
    if (ch + 1 < NT) {
      // counted drain (in-order retirement): ensure stage(ch+1)'s 2 loads
      // retired; keep stage(ch+2)'s 2 loads + this chunk's 4 atomics.
      if (sdiag && ch < 2)
        asm volatile("s_waitcnt vmcnt(2)" ::: "memory");  // no atomics yet
      else if (NT == 2)
        asm volatile("s_waitcnt vmcnt(4)" ::: "memory");
      else
        asm volatile("s_waitcnt vmcnt(6)" ::: "memory");
      __builtin_amdgcn_s_barrier();
    }
  }

  // row sums: reduce over 16 column-lanes, one atomic per row
  #pragma unroll
  for (int st = 0; st < 2; ++st) {
    #pragma unroll
    for (int g = 0; g < 4; ++g) {
      float v = se[st][g];
      #pragma unroll
      for (int m = 1; m <= 8; m <<= 1) v += __shfl_xor(v, m, 64);
      if (lrow == 0) atomicAdd(&rowsum[r0 + 16 * st + kgrp * 4 + g], v);
    }
  }
}

// K3: trivial reduction. lse_i = 10 + LN2*(log2(rowsum_i) - KAPPA);
// pos_i = POS_SCALE * posv[pair(i)] (posv = 256*d, harvested in K2).
__global__ __launch_bounds__(256) void k_rowred(const float* __restrict__ rowsum,
                                               const float* __restrict__ posv,
                                               float* __restrict__ out) {
  __shared__ float ls[4];
  int wave = threadIdx.x >> 6, lane = threadIdx.x & 63;
  float local = 0.0f;
  #pragma unroll
  for (int t = 0; t < 2; ++t) {
    int r = blockIdx.x * 512 + t * 256 + threadIdx.x;
    int pr = (r < HALF_N) ? r : r - HALF_N;
    float lse = 10.0f + LN2 * (__builtin_amdgcn_logf(rowsum[r]) - KAPPA);
    local += lse - POS_SCALE * posv[pr];
  }
  #pragma unroll
  for (int m = 1; m <= 32; m <<= 1) local += __shfl_xor(local, m, 64);
  if (lane == 0) ls[wave] = local;
  __syncthreads();
  if (threadIdx.x == 0)
    atomicAdd(out, (ls[0] + ls[1] + ls[2] + ls[3]) * (1.0f / TWO_N));
}

extern "C" void kernel_launch(void* const* d_in, const int* in_sizes, int n_in,
                              void* d_out, int out_size, void* d_ws, size_t ws_size,
                              hipStream_t stream) {
  const float* zi = (const float*)d_in[0];
  const float* zj = (const float*)d_in[1];
  unsigned char* rn4 = (unsigned char*)d_ws;                        // 1 MB
  float* rowsum = (float*)((char*)d_ws + (size_t)TWO_N * DIM / 2);  // 32 KB
  float* posv = rowsum + TWO_N;                                     // 16 KB
  float* out = (float*)d_out;

  hipLaunchKernelGGL(k_norm, dim3(TWO_N / 16), dim3(256), 0, stream,
                     zi, zj, rn4, rowsum, out);
  hipLaunchKernelGGL(k_sim, dim3(NBLK, 9), dim3(256), 0, stream,
                     rn4, rowsum, posv);
  hipLaunchKernelGGL(k_rowred, dim3(TWO_N / 512), dim3(256), 0, stream,
                     rowsum, posv, out);
}